// Round 8
// baseline (244.610 us; speedup 1.0000x reference)
//
#include <hip/hip_runtime.h>

typedef float f4 __attribute__((ext_vector_type(4)));
typedef float f2 __attribute__((ext_vector_type(2)));
typedef short s8 __attribute__((ext_vector_type(8)));

union FU { unsigned u[4]; s8 s; };

// packed f32x2 -> bf16x2 (RNE) in one instruction
__device__ __forceinline__ unsigned cvtpk(float lo, float hi){
  unsigned r;
  asm("v_cvt_pk_bf16_f32 %0, %1, %2" : "=v"(r) : "v"(lo), "v"(hi));
  return r;
}

// ---- bf16 helpers ----
__device__ __forceinline__ float bflo(unsigned v){ return __uint_as_float(v << 16); }
__device__ __forceinline__ float bfhi(unsigned v){ return __uint_as_float(v & 0xFFFF0000u); }

// ---- index loader: handles int32 or int64 edge/batch arrays ----
__device__ __forceinline__ int ld_idx(const void* p, int i, int is64){
  if (is64) return (int)((const long long*)p)[i];
  return ((const int*)p)[i];
}

// wave-level dtype detect (1 => int64): int64 => every odd 32-bit word zero.
__device__ __forceinline__ int detect64(const unsigned* __restrict__ e_raw, int e){
  int lane = threadIdx.x & 63;
  int lim = (e < 1024) ? e : 1024;
  int nz = 0;
  for (int i = lane; i < lim; i += 64) nz |= (e_raw[2*i + 1] != 0u);
  return (__ballot(nz != 0) == 0ull) ? 1 : 0;
}

// ---- MFMA GEMM body: Yb[n,NC](bf16) = X[n,128](f32) @ W[128,NC](f32) ----
template<int NC>
__device__ __forceinline__ void gemm_body(const float* __restrict__ X,
                                          const float* __restrict__ W,
                                          unsigned short* __restrict__ Yb,
                                          int n, int blk, char* Alds){
  constexpr int NCF = NC/16;
  constexpr int WPC = 8/NCF;
  constexpr int RT  = 8/WPC;
  const int tid  = threadIdx.x;
  const int wave = tid >> 6, lane = tid & 63;
  const int rb = blk * 128;
  const f4* X4 = (const f4*)X;

  const int cbase = (wave % NCF) * 16;
  const int rt0   = (wave / NCF) * RT;
  const int col   = cbase + (lane & 15);
  const int kr0   = (lane >> 4) * 8;
  FU bu[4];
#pragma unroll
  for (int ks = 0; ks < 4; ++ks){
    float wv[8];
#pragma unroll
    for (int j = 0; j < 8; ++j) wv[j] = W[(size_t)(ks*32 + kr0 + j)*NC + col];
#pragma unroll
    for (int q = 0; q < 4; ++q) bu[ks].u[q] = cvtpk(wv[2*q], wv[2*q+1]);
  }

  for (int i = tid; i < 128*32; i += 512){
    int row = i >> 5, kq = i & 31;
    int rsrc = rb + row; if (rsrc >= n) rsrc = n - 1;
    f4 xv = X4[(size_t)rsrc*32 + kq];
    unsigned lo = cvtpk(xv[0], xv[1]), hi = cvtpk(xv[2], xv[3]);
    int byte = (row*256 + kq*8) ^ ((row & 7) << 4);
    *reinterpret_cast<uint2*>(Alds + byte) = make_uint2(lo, hi);
  }
  __syncthreads();

  f4 acc[RT];
#pragma unroll
  for (int rt = 0; rt < RT; ++rt) acc[rt] = 0.0f;

#pragma unroll
  for (int rt = 0; rt < RT; ++rt){
    const int arow = (rt0 + rt)*16 + (lane & 15);
#pragma unroll
    for (int ks = 0; ks < 4; ++ks){
      int kb = ks*32 + kr0;
      int byte = (arow*256 + kb*2) ^ ((arow & 7) << 4);
      s8 a = *reinterpret_cast<const s8*>(Alds + byte);
      acc[rt] = __builtin_amdgcn_mfma_f32_16x16x32_bf16(a, bu[ks].s, acc[rt], 0, 0, 0);
    }
  }

#pragma unroll
  for (int rt = 0; rt < RT; ++rt){
    int rowb = rb + (rt0 + rt)*16 + 4*(lane >> 4);
#pragma unroll
    for (int r = 0; r < 4; ++r){
      int row = rowb + r;
      if (row < n) Yb[(size_t)row*NC + col] = (unsigned short)cvtpk(acc[rt][r], acc[rt][r]);
    }
  }
}

template<int NC>
__global__ __launch_bounds__(512) void gemm_k(const float* __restrict__ X,
                                              const float* __restrict__ W,
                                              unsigned short* __restrict__ Yb, int n){
  __shared__ int4 AldsV[2048];
  gemm_body<NC>(X, W, Yb, n, blockIdx.x, (char*)AldsV);
}

// ---- fused: gemm1 (blocks < GB) || bucket-count (LDS hist, no global atomics)
// counts layout: counts[bin*CB + blk] (bin-major for scanB coalescing)
__global__ __launch_bounds__(512) void fused1_k(const float* __restrict__ X,
                                                const float* __restrict__ W1,
                                                unsigned short* __restrict__ Yb,
                                                const void* __restrict__ eidx,
                                                const void* __restrict__ batchp,
                                                int* __restrict__ counts,
                                                int* __restrict__ batch32,
                                                int n, int e, int GB, int CB){
  __shared__ int4 AldsV[2048];
  __shared__ int hist[512];
  int blk = blockIdx.x;
  if (blk < GB){
    gemm_body<128>(X, W1, Yb, n, blk, (char*)AldsV);
    return;
  }
  blk -= GB;                          // 0..CB-1
  const int NBK = (n + 127) >> 7;
  for (int i = threadIdx.x; i < NBK; i += 512) hist[i] = 0;
  __syncthreads();
  int is64 = detect64((const unsigned*)eidx, e);
  int CHK = (e + CB - 1) / CB;
  int beg = blk*CHK, end = min(e, beg + CHK);
  for (int i = beg + (int)threadIdx.x; i < end; i += 512){
    int d = ld_idx(eidx, e + i, is64);
    atomicAdd(&hist[d >> 7], 1);      // LDS atomic
  }
  __syncthreads();
  for (int i = threadIdx.x; i < NBK; i += 512) counts[i*CB + blk] = hist[i];
  // batch conversion spread across count blocks
  for (int i = blk*512 + (int)threadIdx.x; i < n; i += CB*512)
    batch32[i] = ld_idx(batchp, i, is64);
}

// ---- scan: per-(bin,blk) exclusive bases + bucket bases; misc init ----
__global__ __launch_bounds__(512) void scanB_k(const int* __restrict__ counts,
                                               int* __restrict__ base,
                                               int* __restrict__ bb,
                                               int* __restrict__ rowptr,
                                               float* __restrict__ outsum,
                                               int totalOut, int CB, int NBK,
                                               int n, int e){
  __shared__ int tot[512];
  int tid = threadIdx.x;
  int myTot = 0;
  if (tid < NBK){
    int run = 0;
    const int* c = counts + tid*CB;
    int* bs = base + tid*CB;
    for (int b = 0; b < CB; ++b){ bs[b] = run; run += c[b]; }
    myTot = run;
  }
  tot[tid] = myTot;
  __syncthreads();
  for (int o = 1; o < 512; o <<= 1){
    int v = (tid >= o) ? tot[tid - o] : 0;
    __syncthreads();
    tot[tid] += v;
    __syncthreads();
  }
  if (tid < NBK) bb[tid] = tot[tid] - myTot;    // exclusive bucket base
  if (tid == 0){ bb[NBK] = e; rowptr[n] = e; }
  for (int k = tid; k < totalOut; k += 512) outsum[k] = 0.0f;
}

// ---- scatter edges into bucket-grouped array (LDS cursors, global posns) ----
__global__ __launch_bounds__(512) void scat_k(const void* __restrict__ eidx,
                                              const int* __restrict__ base,
                                              const int* __restrict__ bb,
                                              int* __restrict__ packed,
                                              int n, int e, int CB){
  __shared__ int cur[512];
  int blk = blockIdx.x, tid = threadIdx.x;
  const int NBK = (n + 127) >> 7;
  for (int i = tid; i < NBK; i += 512) cur[i] = bb[i] + base[i*CB + blk];
  __syncthreads();
  int is64 = detect64((const unsigned*)eidx, e);
  int CHK = (e + CB - 1) / CB;
  int beg = blk*CHK, end = min(e, beg + CHK);
  for (int i = beg + tid; i < end; i += 512){
    int s = ld_idx(eidx, i, is64);
    int d = ld_idx(eidx, e + i, is64);
    int pos = atomicAdd(&cur[d >> 7], 1);
    packed[pos] = s | ((d & 127) << 16);
  }
}

// ---- per-bucket CSR build: 128-bin LDS counting sort, degrees, dinv ----
#define CSR_CAP 6144
__global__ __launch_bounds__(256) void csr_k(const int* __restrict__ packed,
                                             const int* __restrict__ bb,
                                             int* __restrict__ esrcS,
                                             int* __restrict__ rowptr,
                                             float* __restrict__ dinv, int n){
  __shared__ int vals[CSR_CAP];
  __shared__ int hist[128], off[128], cur[128];
  int b = blockIdx.x, tid = threadIdx.x;
  int sbeg = bb[b], send = bb[b + 1];
  int m = send - sbeg;
  int mL = min(m, CSR_CAP);
  for (int i = tid; i < mL; i += 256) vals[i] = packed[sbeg + i];
  if (tid < 128) hist[tid] = 0;
  __syncthreads();
  for (int i = tid; i < m; i += 256){
    int v = (i < CSR_CAP) ? vals[i] : packed[sbeg + i];
    atomicAdd(&hist[(v >> 16) & 127], 1);
  }
  __syncthreads();
  if (tid < 128) off[tid] = hist[tid];
  __syncthreads();
  for (int o = 1; o < 128; o <<= 1){
    int v = 0;
    if (tid < 128 && tid >= o) v = off[tid - o];
    __syncthreads();
    if (tid < 128) off[tid] += v;
    __syncthreads();
  }
  if (tid < 128){
    int ex = off[tid] - hist[tid];      // exclusive
    cur[tid] = ex;
    int node = b*128 + tid;
    if (node < n){
      rowptr[node] = sbeg + ex;
      dinv[node] = rsqrtf((float)hist[tid] + 1.0f);
    }
  }
  __syncthreads();
  for (int i = tid; i < m; i += 256){
    int v = (i < CSR_CAP) ? vals[i] : packed[sbeg + i];
    int pos = atomicAdd(&cur[(v >> 16) & 127], 1);
    esrcS[sbeg + pos] = v & 0xFFFF;
  }
}

// ---- CSR aggregation + bias + relu: one wave per node, bf16 gathers,
// unroll-by-8 MLP; weight = dinv[s]*dinv[d] computed on the fly ----
template<int NC>
__global__ __launch_bounds__(256) void agg_k(const unsigned short* __restrict__ HWb,
                                             const float* __restrict__ dinv,
                                             const int* __restrict__ rowptr,
                                             const int* __restrict__ esrcS,
                                             const float* __restrict__ bias,
                                             float* __restrict__ Hout, int n){
  int wid  = (blockIdx.x*256 + threadIdx.x) >> 6;
  int lane = threadIdx.x & 63;
  if (wid >= n) return;
  wid = __builtin_amdgcn_readfirstlane(wid);
  float di = dinv[wid];
  float di2 = di * di;
  int beg = __builtin_amdgcn_readfirstlane(rowptr[wid]);
  int end = __builtin_amdgcn_readfirstlane(rowptr[wid + 1]);
  if (NC == 128){
    unsigned sv = ((const unsigned*)(HWb + (size_t)wid*128))[lane];
    f2 acc;
    acc[0] = bflo(sv) * di2;
    acc[1] = bfhi(sv) * di2;
    int j = beg;
    for (; j + 8 <= end; j += 8){
      int s[8]; float dv[8]; unsigned v[8];
#pragma unroll
      for (int t = 0; t < 8; ++t) s[t] = esrcS[j + t];
#pragma unroll
      for (int t = 0; t < 8; ++t){
        dv[t] = dinv[s[t]];
        v[t] = ((const unsigned*)(HWb + (size_t)s[t]*128))[lane];
      }
#pragma unroll
      for (int t = 0; t < 8; ++t){
        float wt = dv[t] * di;
        acc[0] += bflo(v[t]) * wt;
        acc[1] += bfhi(v[t]) * wt;
      }
    }
    if (j + 4 <= end){
      int s[4]; float dv[4]; unsigned v[4];
#pragma unroll
      for (int t = 0; t < 4; ++t) s[t] = esrcS[j + t];
#pragma unroll
      for (int t = 0; t < 4; ++t){
        dv[t] = dinv[s[t]];
        v[t] = ((const unsigned*)(HWb + (size_t)s[t]*128))[lane];
      }
#pragma unroll
      for (int t = 0; t < 4; ++t){
        float wt = dv[t] * di;
        acc[0] += bflo(v[t]) * wt;
        acc[1] += bfhi(v[t]) * wt;
      }
      j += 4;
    }
    for (; j < end; ++j){
      int s = esrcS[j];
      float wt = dinv[s] * di;
      unsigned v = ((const unsigned*)(HWb + (size_t)s*128))[lane];
      acc[0] += bflo(v) * wt;
      acc[1] += bfhi(v) * wt;
    }
    f2 bb2 = ((const f2*)bias)[lane];
    acc += bb2;
    acc[0] = fmaxf(acc[0], 0.0f);
    acc[1] = fmaxf(acc[1], 0.0f);
    ((f2*)Hout)[(size_t)wid*64 + lane] = acc;
  } else {
    float acc = bflo((unsigned)HWb[(size_t)wid*64 + lane]) * di2;
    int j = beg;
    for (; j + 8 <= end; j += 8){
      int s[8]; float dv[8]; unsigned v[8];
#pragma unroll
      for (int t = 0; t < 8; ++t) s[t] = esrcS[j + t];
#pragma unroll
      for (int t = 0; t < 8; ++t){
        dv[t] = dinv[s[t]];
        v[t] = (unsigned)HWb[(size_t)s[t]*64 + lane];
      }
#pragma unroll
      for (int t = 0; t < 8; ++t) acc += bflo(v[t]) * (dv[t] * di);
    }
    if (j + 4 <= end){
      int s[4]; float dv[4]; unsigned v[4];
#pragma unroll
      for (int t = 0; t < 4; ++t) s[t] = esrcS[j + t];
#pragma unroll
      for (int t = 0; t < 4; ++t){
        dv[t] = dinv[s[t]];
        v[t] = (unsigned)HWb[(size_t)s[t]*64 + lane];
      }
#pragma unroll
      for (int t = 0; t < 4; ++t) acc += bflo(v[t]) * (dv[t] * di);
      j += 4;
    }
    for (; j < end; ++j){
      int s = esrcS[j];
      acc += bflo((unsigned)HWb[(size_t)s*64 + lane]) * (dinv[s] * di);
    }
    acc = fmaxf(acc + bias[lane], 0.0f);
    Hout[(size_t)wid*64 + lane] = acc;
  }
}

// ---- mean pool: 8 nodes per wave, unrolled loads, run-length atomics ----
__global__ __launch_bounds__(256) void pool_k(const float* __restrict__ H2,
                                              const int* __restrict__ batch32,
                                              float* __restrict__ outsum, int n){
  int wid  = (blockIdx.x*256 + threadIdx.x) >> 6;
  int lane = threadIdx.x & 63;
  int start = wid * 8;
  if (start >= n) return;
  int cnt = min(8, n - start);
  float v[8]; int b[8];
#pragma unroll
  for (int t = 0; t < 8; ++t){
    int i = start + t; if (i >= n) i = n - 1;
    v[t] = H2[(size_t)i*64 + lane];
    b[t] = batch32[i];
  }
  float acc = 0.0f;
  int gcur = b[0];
#pragma unroll
  for (int t = 0; t < 8; ++t){
    if (t < cnt){
      if (b[t] != gcur){
        unsafeAtomicAdd(&outsum[gcur*64 + lane], acc);
        acc = 0.0f; gcur = b[t];
      }
      acc += v[t];
    }
  }
  unsafeAtomicAdd(&outsum[gcur*64 + lane], acc);
}

// ---- finalize: graph sizes via binary search on sorted batch + divide ----
__global__ void fin_k(const float* __restrict__ outsum,
                      const int* __restrict__ batch32,
                      float* __restrict__ out, int n, int g){
  __shared__ int starts[257];
  int t = threadIdx.x;
  if (t <= g){
    int lo = 0, hi = n;
    while (lo < hi){ int mid = (lo + hi) >> 1; if (batch32[mid] < t) lo = mid + 1; else hi = mid; }
    starts[t] = lo;
  }
  __syncthreads();
  for (int idx = t; idx < (g << 6); idx += 256){
    int gi = idx >> 6;
    float c = (float)(starts[gi + 1] - starts[gi]);
    out[idx] = outsum[idx] / fmaxf(c, 1.0f);
  }
}

extern "C" void kernel_launch(void* const* d_in, const int* in_sizes, int n_in,
                              void* d_out, int out_size, void* d_ws, size_t ws_size,
                              hipStream_t stream){
  const float* x    = (const float*)d_in[0];
  const float* W1   = (const float*)d_in[1];
  const float* b1   = (const float*)d_in[2];
  const float* W2   = (const float*)d_in[3];
  const float* b2   = (const float*)d_in[4];
  const void*  eidx = d_in[5];
  const void*  batchp = d_in[6];
  const int n = in_sizes[0] / 128;    // 50000
  const int e = in_sizes[5] / 2;      // 800000
  const int g = out_size / 64;        // 64 graphs
  float* out = (float*)d_out;

  const int NBK = (n + 127) >> 7;     // dst buckets (assumes n <= 65536)
  const int CB  = 256;                // count/scatter blocks
  const int GB  = (n + 127) / 128;    // gemm M-tiles

  // ---- workspace layout ----
  char* w = (char*)d_ws;
  int* counts  = (int*)w;                     // NBK*CB   (bin-major)
  int* base    = counts + (size_t)NBK*CB;     // NBK*CB
  int* bb      = base + (size_t)NBK*CB;       // NBK+1
  int* rowptr  = bb + (NBK + 1);              // n+1
  int* batch32 = rowptr + (n + 1);            // n
  float* dinv  = (float*)(batch32 + n);       // n
  float* outsum = dinv + n;                   // out_size
  int* packed  = (int*)(outsum + out_size);   // e
  int* esrcS   = packed + e;                  // e
  size_t ofs = (size_t)((char*)(esrcS + e) - w);
  ofs = (ofs + 255) & ~(size_t)255;
  unsigned short* HWb = (unsigned short*)(w + ofs);   // n*128 bf16
  size_t ofs2 = ofs + (size_t)n * 128 * 2;
  ofs2 = (ofs2 + 255) & ~(size_t)255;
  float* H = (float*)(w + ofs2);              // n*128 f32

  fused1_k<<<GB + CB, 512, 0, stream>>>(x, W1, HWb, eidx, batchp,
                                        counts, batch32, n, e, GB, CB);
  scanB_k<<<1, 512, 0, stream>>>(counts, base, bb, rowptr, outsum,
                                 out_size, CB, NBK, n, e);
  scat_k<<<CB, 512, 0, stream>>>(eidx, base, bb, packed, n, e, CB);
  csr_k<<<NBK, 256, 0, stream>>>(packed, bb, esrcS, rowptr, dinv, n);

  agg_k<128><<<(n + 3)/4, 256, 0, stream>>>(HWb, dinv, rowptr, esrcS, b1, H, n);
  gemm_k<64><<<GB, 512, 0, stream>>>(H, W2, HWb, n);
  agg_k<64><<<(n + 3)/4, 256, 0, stream>>>(HWb, dinv, rowptr, esrcS, b2, H, n);

  int pw = (n + 7)/8;
  pool_k<<<(pw + 3)/4, 256, 0, stream>>>(H, batch32, outsum, n);
  fin_k<<<1, 256, 0, stream>>>(outsum, batch32, out, n, g);
}

// Round 9
// 128.725 us; speedup vs baseline: 1.9003x; 1.9003x over previous
//
#include <hip/hip_runtime.h>

typedef float f4 __attribute__((ext_vector_type(4)));
typedef float f2 __attribute__((ext_vector_type(2)));
typedef short s8 __attribute__((ext_vector_type(8)));

union FU { unsigned u[4]; s8 s; };

// packed f32x2 -> bf16x2 (RNE) in one instruction
__device__ __forceinline__ unsigned cvtpk(float lo, float hi){
  unsigned r;
  asm("v_cvt_pk_bf16_f32 %0, %1, %2" : "=v"(r) : "v"(lo), "v"(hi));
  return r;
}

// ---- bf16 helpers ----
__device__ __forceinline__ float bflo(unsigned v){ return __uint_as_float(v << 16); }
__device__ __forceinline__ float bfhi(unsigned v){ return __uint_as_float(v & 0xFFFF0000u); }

// ---- index loader: handles int32 or int64 edge/batch arrays ----
__device__ __forceinline__ int ld_idx(const void* p, int i, int is64){
  if (is64) return (int)((const long long*)p)[i];
  return ((const int*)p)[i];
}

// wave-level dtype detect (1 => int64): int64 => every odd 32-bit word zero.
__device__ __forceinline__ int detect64(const unsigned* __restrict__ e_raw, int e){
  int lane = threadIdx.x & 63;
  int lim = (e < 1024) ? e : 1024;
  int nz = 0;
  for (int i = lane; i < lim; i += 64) nz |= (e_raw[2*i + 1] != 0u);
  return (__ballot(nz != 0) == 0ull) ? 1 : 0;
}

// ---- MFMA GEMM body: Yb[n,NC](bf16) = X[n,128](f32) @ W[128,NC](f32) ----
template<int NC>
__device__ __forceinline__ void gemm_body(const float* __restrict__ X,
                                          const float* __restrict__ W,
                                          unsigned short* __restrict__ Yb,
                                          int n, int blk, char* Alds){
  constexpr int NCF = NC/16;
  constexpr int WPC = 8/NCF;
  constexpr int RT  = 8/WPC;
  const int tid  = threadIdx.x;
  const int wave = tid >> 6, lane = tid & 63;
  const int rb = blk * 128;
  const f4* X4 = (const f4*)X;

  const int cbase = (wave % NCF) * 16;
  const int rt0   = (wave / NCF) * RT;
  const int col   = cbase + (lane & 15);
  const int kr0   = (lane >> 4) * 8;
  FU bu[4];
#pragma unroll
  for (int ks = 0; ks < 4; ++ks){
    float wv[8];
#pragma unroll
    for (int j = 0; j < 8; ++j) wv[j] = W[(size_t)(ks*32 + kr0 + j)*NC + col];
#pragma unroll
    for (int q = 0; q < 4; ++q) bu[ks].u[q] = cvtpk(wv[2*q], wv[2*q+1]);
  }

  for (int i = tid; i < 128*32; i += 512){
    int row = i >> 5, kq = i & 31;
    int rsrc = rb + row; if (rsrc >= n) rsrc = n - 1;
    f4 xv = X4[(size_t)rsrc*32 + kq];
    unsigned lo = cvtpk(xv[0], xv[1]), hi = cvtpk(xv[2], xv[3]);
    int byte = (row*256 + kq*8) ^ ((row & 7) << 4);
    *reinterpret_cast<uint2*>(Alds + byte) = make_uint2(lo, hi);
  }
  __syncthreads();

  f4 acc[RT];
#pragma unroll
  for (int rt = 0; rt < RT; ++rt) acc[rt] = 0.0f;

#pragma unroll
  for (int rt = 0; rt < RT; ++rt){
    const int arow = (rt0 + rt)*16 + (lane & 15);
#pragma unroll
    for (int ks = 0; ks < 4; ++ks){
      int kb = ks*32 + kr0;
      int byte = (arow*256 + kb*2) ^ ((arow & 7) << 4);
      s8 a = *reinterpret_cast<const s8*>(Alds + byte);
      acc[rt] = __builtin_amdgcn_mfma_f32_16x16x32_bf16(a, bu[ks].s, acc[rt], 0, 0, 0);
    }
  }

#pragma unroll
  for (int rt = 0; rt < RT; ++rt){
    int rowb = rb + (rt0 + rt)*16 + 4*(lane >> 4);
#pragma unroll
    for (int r = 0; r < 4; ++r){
      int row = rowb + r;
      if (row < n) Yb[(size_t)row*NC + col] = (unsigned short)cvtpk(acc[rt][r], acc[rt][r]);
    }
  }
}

template<int NC>
__global__ __launch_bounds__(512) void gemm_k(const float* __restrict__ X,
                                              const float* __restrict__ W,
                                              unsigned short* __restrict__ Yb, int n){
  __shared__ int4 AldsV[2048];
  gemm_body<NC>(X, W, Yb, n, blockIdx.x, (char*)AldsV);
}

// ---- fused: gemm1 (blocks < GB) || bucket-count (LDS hist, no global atomics)
// counts layout: counts[bin*CB + blk] (bin-major flat order)
__global__ __launch_bounds__(512) void fused1_k(const float* __restrict__ X,
                                                const float* __restrict__ W1,
                                                unsigned short* __restrict__ Yb,
                                                const void* __restrict__ eidx,
                                                const void* __restrict__ batchp,
                                                int* __restrict__ counts,
                                                int* __restrict__ batch32,
                                                int n, int e, int GB, int CB){
  __shared__ int4 AldsV[2048];
  __shared__ int hist[512];
  int blk = blockIdx.x;
  if (blk < GB){
    gemm_body<128>(X, W1, Yb, n, blk, (char*)AldsV);
    return;
  }
  blk -= GB;                          // 0..CB-1
  const int NBK = (n + 127) >> 7;
  for (int i = threadIdx.x; i < NBK; i += 512) hist[i] = 0;
  __syncthreads();
  int is64 = detect64((const unsigned*)eidx, e);
  int CHK = (e + CB - 1) / CB;
  int beg = blk*CHK, end = min(e, beg + CHK);
  for (int i = beg + (int)threadIdx.x; i < end; i += 512){
    int d = ld_idx(eidx, e + i, is64);
    atomicAdd(&hist[d >> 7], 1);      // LDS atomic
  }
  __syncthreads();
  for (int i = threadIdx.x; i < NBK; i += 512) counts[i*CB + blk] = hist[i];
  // batch conversion spread across count blocks
  for (int i = blk*512 + (int)threadIdx.x; i < n; i += CB*512)
    batch32[i] = ld_idx(batchp, i, is64);
}

// ---- flat hierarchical exclusive scan of counts[L] (bin-major) ----
// level 1: block-local exclusive scan + block sums
__global__ void scanA_k(const int* __restrict__ counts, int* __restrict__ base,
                        int* __restrict__ bsum, int L){
  __shared__ int sh[256];
  int tid = threadIdx.x;
  int i = blockIdx.x*256 + tid;
  int v = (i < L) ? counts[i] : 0;
  sh[tid] = v; __syncthreads();
  for (int off = 1; off < 256; off <<= 1){
    int t = (tid >= off) ? sh[tid - off] : 0;
    __syncthreads();
    sh[tid] += t;
    __syncthreads();
  }
  if (i < L) base[i] = sh[tid] - v;
  if (tid == 255) bsum[blockIdx.x] = sh[255];
}

// level 2: single block scans block sums (nb <= 512); also zero outsum
__global__ __launch_bounds__(512) void scanB2_k(int* __restrict__ bsum, int nb,
                                                float* __restrict__ outsum,
                                                int totalOut){
  __shared__ int sh[512];
  int tid = threadIdx.x;
  int v = (tid < nb) ? bsum[tid] : 0;
  sh[tid] = v; __syncthreads();
  for (int off = 1; off < 512; off <<= 1){
    int t = (tid >= off) ? sh[tid - off] : 0;
    __syncthreads();
    sh[tid] += t;
    __syncthreads();
  }
  if (tid < nb) bsum[tid] = sh[tid] - v;      // exclusive
  for (int k = tid; k < totalOut; k += 512) outsum[k] = 0.0f;
}

// level 3: add block offsets; extract bucket bases bb[bin] = scan[bin*CB]
__global__ void scanC_k(int* __restrict__ base, const int* __restrict__ bsum,
                        int* __restrict__ bb, int* __restrict__ rowptr,
                        int L, int CB, int NBK, int n, int e){
  int i = blockIdx.x*256 + threadIdx.x;
  if (i < L){
    int vfin = base[i] + bsum[i >> 8];
    base[i] = vfin;
    if ((i & (CB - 1)) == 0) bb[i / CB] = vfin;   // CB is pow2
  }
  if (i == 0){ bb[NBK] = e; rowptr[n] = e; }
}

// ---- scatter edges into bucket-grouped array (LDS cursors, flat-scan posns) ----
__global__ __launch_bounds__(512) void scat_k(const void* __restrict__ eidx,
                                              const int* __restrict__ base,
                                              int* __restrict__ packed,
                                              int n, int e, int CB){
  __shared__ int cur[512];
  int blk = blockIdx.x, tid = threadIdx.x;
  const int NBK = (n + 127) >> 7;
  for (int i = tid; i < NBK; i += 512) cur[i] = base[i*CB + blk];  // global posn
  __syncthreads();
  int is64 = detect64((const unsigned*)eidx, e);
  int CHK = (e + CB - 1) / CB;
  int beg = blk*CHK, end = min(e, beg + CHK);
  for (int i = beg + tid; i < end; i += 512){
    int s = ld_idx(eidx, i, is64);
    int d = ld_idx(eidx, e + i, is64);
    int pos = atomicAdd(&cur[d >> 7], 1);
    packed[pos] = s | ((d & 127) << 16);
  }
}

// ---- per-bucket CSR build: 128-bin LDS counting sort, degrees, dinv ----
#define CSR_CAP 6144
__global__ __launch_bounds__(256) void csr_k(const int* __restrict__ packed,
                                             const int* __restrict__ bb,
                                             int* __restrict__ esrcS,
                                             int* __restrict__ rowptr,
                                             float* __restrict__ dinv, int n){
  __shared__ int vals[CSR_CAP];
  __shared__ int hist[128], off[128], cur[128];
  int b = blockIdx.x, tid = threadIdx.x;
  int sbeg = bb[b], send = bb[b + 1];
  int m = send - sbeg;
  int mL = min(m, CSR_CAP);
  for (int i = tid; i < mL; i += 256) vals[i] = packed[sbeg + i];
  if (tid < 128) hist[tid] = 0;
  __syncthreads();
  for (int i = tid; i < m; i += 256){
    int v = (i < CSR_CAP) ? vals[i] : packed[sbeg + i];
    atomicAdd(&hist[(v >> 16) & 127], 1);
  }
  __syncthreads();
  if (tid < 128) off[tid] = hist[tid];
  __syncthreads();
  for (int o = 1; o < 128; o <<= 1){
    int v = 0;
    if (tid < 128 && tid >= o) v = off[tid - o];
    __syncthreads();
    if (tid < 128) off[tid] += v;
    __syncthreads();
  }
  if (tid < 128){
    int ex = off[tid] - hist[tid];      // exclusive
    cur[tid] = ex;
    int node = b*128 + tid;
    if (node < n){
      rowptr[node] = sbeg + ex;
      dinv[node] = rsqrtf((float)hist[tid] + 1.0f);
    }
  }
  __syncthreads();
  for (int i = tid; i < m; i += 256){
    int v = (i < CSR_CAP) ? vals[i] : packed[sbeg + i];
    int pos = atomicAdd(&cur[(v >> 16) & 127], 1);
    esrcS[sbeg + pos] = v & 0xFFFF;
  }
}

// ---- CSR aggregation + bias + relu: one wave per node, bf16 gathers,
// unroll-by-8 MLP; weight = dinv[s]*dinv[d] computed on the fly ----
template<int NC>
__global__ __launch_bounds__(256) void agg_k(const unsigned short* __restrict__ HWb,
                                             const float* __restrict__ dinv,
                                             const int* __restrict__ rowptr,
                                             const int* __restrict__ esrcS,
                                             const float* __restrict__ bias,
                                             float* __restrict__ Hout, int n){
  int wid  = (blockIdx.x*256 + threadIdx.x) >> 6;
  int lane = threadIdx.x & 63;
  if (wid >= n) return;
  wid = __builtin_amdgcn_readfirstlane(wid);
  float di = dinv[wid];
  float di2 = di * di;
  int beg = __builtin_amdgcn_readfirstlane(rowptr[wid]);
  int end = __builtin_amdgcn_readfirstlane(rowptr[wid + 1]);
  if (NC == 128){
    unsigned sv = ((const unsigned*)(HWb + (size_t)wid*128))[lane];
    f2 acc;
    acc[0] = bflo(sv) * di2;
    acc[1] = bfhi(sv) * di2;
    int j = beg;
    for (; j + 8 <= end; j += 8){
      int s[8]; float dv[8]; unsigned v[8];
#pragma unroll
      for (int t = 0; t < 8; ++t) s[t] = esrcS[j + t];
#pragma unroll
      for (int t = 0; t < 8; ++t){
        dv[t] = dinv[s[t]];
        v[t] = ((const unsigned*)(HWb + (size_t)s[t]*128))[lane];
      }
#pragma unroll
      for (int t = 0; t < 8; ++t){
        float wt = dv[t] * di;
        acc[0] += bflo(v[t]) * wt;
        acc[1] += bfhi(v[t]) * wt;
      }
    }
    if (j + 4 <= end){
      int s[4]; float dv[4]; unsigned v[4];
#pragma unroll
      for (int t = 0; t < 4; ++t) s[t] = esrcS[j + t];
#pragma unroll
      for (int t = 0; t < 4; ++t){
        dv[t] = dinv[s[t]];
        v[t] = ((const unsigned*)(HWb + (size_t)s[t]*128))[lane];
      }
#pragma unroll
      for (int t = 0; t < 4; ++t){
        float wt = dv[t] * di;
        acc[0] += bflo(v[t]) * wt;
        acc[1] += bfhi(v[t]) * wt;
      }
      j += 4;
    }
    for (; j < end; ++j){
      int s = esrcS[j];
      float wt = dinv[s] * di;
      unsigned v = ((const unsigned*)(HWb + (size_t)s*128))[lane];
      acc[0] += bflo(v) * wt;
      acc[1] += bfhi(v) * wt;
    }
    f2 bb2 = ((const f2*)bias)[lane];
    acc += bb2;
    acc[0] = fmaxf(acc[0], 0.0f);
    acc[1] = fmaxf(acc[1], 0.0f);
    ((f2*)Hout)[(size_t)wid*64 + lane] = acc;
  } else {
    float acc = bflo((unsigned)HWb[(size_t)wid*64 + lane]) * di2;
    int j = beg;
    for (; j + 8 <= end; j += 8){
      int s[8]; float dv[8]; unsigned v[8];
#pragma unroll
      for (int t = 0; t < 8; ++t) s[t] = esrcS[j + t];
#pragma unroll
      for (int t = 0; t < 8; ++t){
        dv[t] = dinv[s[t]];
        v[t] = (unsigned)HWb[(size_t)s[t]*64 + lane];
      }
#pragma unroll
      for (int t = 0; t < 8; ++t) acc += bflo(v[t]) * (dv[t] * di);
    }
    if (j + 4 <= end){
      int s[4]; float dv[4]; unsigned v[4];
#pragma unroll
      for (int t = 0; t < 4; ++t) s[t] = esrcS[j + t];
#pragma unroll
      for (int t = 0; t < 4; ++t){
        dv[t] = dinv[s[t]];
        v[t] = (unsigned)HWb[(size_t)s[t]*64 + lane];
      }
#pragma unroll
      for (int t = 0; t < 4; ++t) acc += bflo(v[t]) * (dv[t] * di);
      j += 4;
    }
    for (; j < end; ++j){
      int s = esrcS[j];
      acc += bflo((unsigned)HWb[(size_t)s*64 + lane]) * (dinv[s] * di);
    }
    acc = fmaxf(acc + bias[lane], 0.0f);
    Hout[(size_t)wid*64 + lane] = acc;
  }
}

// ---- mean pool: 8 nodes per wave, unrolled loads, run-length atomics ----
__global__ __launch_bounds__(256) void pool_k(const float* __restrict__ H2,
                                              const int* __restrict__ batch32,
                                              float* __restrict__ outsum, int n){
  int wid  = (blockIdx.x*256 + threadIdx.x) >> 6;
  int lane = threadIdx.x & 63;
  int start = wid * 8;
  if (start >= n) return;
  int cnt = min(8, n - start);
  float v[8]; int b[8];
#pragma unroll
  for (int t = 0; t < 8; ++t){
    int i = start + t; if (i >= n) i = n - 1;
    v[t] = H2[(size_t)i*64 + lane];
    b[t] = batch32[i];
  }
  float acc = 0.0f;
  int gcur = b[0];
#pragma unroll
  for (int t = 0; t < 8; ++t){
    if (t < cnt){
      if (b[t] != gcur){
        unsafeAtomicAdd(&outsum[gcur*64 + lane], acc);
        acc = 0.0f; gcur = b[t];
      }
      acc += v[t];
    }
  }
  unsafeAtomicAdd(&outsum[gcur*64 + lane], acc);
}

// ---- finalize: graph sizes via binary search on sorted batch + divide ----
__global__ void fin_k(const float* __restrict__ outsum,
                      const int* __restrict__ batch32,
                      float* __restrict__ out, int n, int g){
  __shared__ int starts[257];
  int t = threadIdx.x;
  if (t <= g){
    int lo = 0, hi = n;
    while (lo < hi){ int mid = (lo + hi) >> 1; if (batch32[mid] < t) lo = mid + 1; else hi = mid; }
    starts[t] = lo;
  }
  __syncthreads();
  for (int idx = t; idx < (g << 6); idx += 256){
    int gi = idx >> 6;
    float c = (float)(starts[gi + 1] - starts[gi]);
    out[idx] = outsum[idx] / fmaxf(c, 1.0f);
  }
}

extern "C" void kernel_launch(void* const* d_in, const int* in_sizes, int n_in,
                              void* d_out, int out_size, void* d_ws, size_t ws_size,
                              hipStream_t stream){
  const float* x    = (const float*)d_in[0];
  const float* W1   = (const float*)d_in[1];
  const float* b1   = (const float*)d_in[2];
  const float* W2   = (const float*)d_in[3];
  const float* b2   = (const float*)d_in[4];
  const void*  eidx = d_in[5];
  const void*  batchp = d_in[6];
  const int n = in_sizes[0] / 128;    // 50000
  const int e = in_sizes[5] / 2;      // 800000
  const int g = out_size / 64;        // 64 graphs
  float* out = (float*)d_out;

  const int NBK = (n + 127) >> 7;     // dst buckets (assumes n <= 65536)
  const int CB  = 256;                // count/scatter blocks (pow2)
  const int GB  = (n + 127) / 128;    // gemm M-tiles
  const int L   = NBK * CB;           // flat counts length

  // ---- workspace layout ----
  char* w = (char*)d_ws;
  int* counts  = (int*)w;                     // L   (bin-major)
  int* base    = counts + (size_t)L;          // L
  int* bsum    = base + (size_t)L;            // ceil(L/256)
  int  nb2     = (L + 255) / 256;
  int* bb      = bsum + nb2;                  // NBK+1
  int* rowptr  = bb + (NBK + 1);              // n+1
  int* batch32 = rowptr + (n + 1);            // n
  float* dinv  = (float*)(batch32 + n);       // n
  float* outsum = dinv + n;                   // out_size
  int* packed  = (int*)(outsum + out_size);   // e
  int* esrcS   = packed + e;                  // e
  size_t ofs = (size_t)((char*)(esrcS + e) - w);
  ofs = (ofs + 255) & ~(size_t)255;
  unsigned short* HWb = (unsigned short*)(w + ofs);   // n*128 bf16
  size_t ofs2 = ofs + (size_t)n * 128 * 2;
  ofs2 = (ofs2 + 255) & ~(size_t)255;
  float* H = (float*)(w + ofs2);              // n*128 f32

  fused1_k<<<GB + CB, 512, 0, stream>>>(x, W1, HWb, eidx, batchp,
                                        counts, batch32, n, e, GB, CB);
  scanA_k<<<nb2, 256, 0, stream>>>(counts, base, bsum, L);
  scanB2_k<<<1, 512, 0, stream>>>(bsum, nb2, outsum, out_size);
  scanC_k<<<nb2, 256, 0, stream>>>(base, bsum, bb, rowptr, L, CB, NBK, n, e);
  scat_k<<<CB, 512, 0, stream>>>(eidx, base, packed, n, e, CB);
  csr_k<<<NBK, 256, 0, stream>>>(packed, bb, esrcS, rowptr, dinv, n);

  agg_k<128><<<(n + 3)/4, 256, 0, stream>>>(HWb, dinv, rowptr, esrcS, b1, H, n);
  gemm_k<64><<<GB, 512, 0, stream>>>(H, W2, HWb, n);
  agg_k<64><<<(n + 3)/4, 256, 0, stream>>>(HWb, dinv, rowptr, esrcS, b2, H, n);

  int pw = (n + 7)/8;
  pool_k<<<(pw + 3)/4, 256, 0, stream>>>(H, batch32, outsum, n);
  fin_k<<<1, 256, 0, stream>>>(outsum, batch32, out, n, g);
}

// Round 10
// 124.139 us; speedup vs baseline: 1.9704x; 1.0369x over previous
//
#include <hip/hip_runtime.h>

typedef float f4 __attribute__((ext_vector_type(4)));
typedef float f2 __attribute__((ext_vector_type(2)));
typedef short s8 __attribute__((ext_vector_type(8)));

union FU { unsigned u[4]; s8 s; };

// packed f32x2 -> bf16x2 (RNE) in one instruction
__device__ __forceinline__ unsigned cvtpk(float lo, float hi){
  unsigned r;
  asm("v_cvt_pk_bf16_f32 %0, %1, %2" : "=v"(r) : "v"(lo), "v"(hi));
  return r;
}

// ---- bf16 helpers ----
__device__ __forceinline__ float bflo(unsigned v){ return __uint_as_float(v << 16); }
__device__ __forceinline__ float bfhi(unsigned v){ return __uint_as_float(v & 0xFFFF0000u); }

// ---- index loader: handles int32 or int64 edge/batch arrays ----
__device__ __forceinline__ int ld_idx(const void* p, int i, int is64){
  if (is64) return (int)((const long long*)p)[i];
  return ((const int*)p)[i];
}

// wave-level dtype detect (1 => int64): int64 => every odd 32-bit word zero.
__device__ __forceinline__ int detect64(const unsigned* __restrict__ e_raw, int e){
  int lane = threadIdx.x & 63;
  int lim = (e < 1024) ? e : 1024;
  int nz = 0;
  for (int i = lane; i < lim; i += 64) nz |= (e_raw[2*i + 1] != 0u);
  return (__ballot(nz != 0) == 0ull) ? 1 : 0;
}

// ---- MFMA GEMM body: Yb[n,NC](bf16) = X[n,128] @ W[128,NC](f32)
// BIN=0: X is f32 (converted during staging); BIN=1: X already bf16.
template<int NC, int BIN>
__device__ __forceinline__ void gemm_body(const void* __restrict__ Xv,
                                          const float* __restrict__ W,
                                          unsigned short* __restrict__ Yb,
                                          int n, int blk, char* Alds){
  constexpr int NCF = NC/16;
  constexpr int WPC = 8/NCF;
  constexpr int RT  = 8/WPC;
  const int tid  = threadIdx.x;
  const int wave = tid >> 6, lane = tid & 63;
  const int rb = blk * 128;

  const int cbase = (wave % NCF) * 16;
  const int rt0   = (wave / NCF) * RT;
  const int col   = cbase + (lane & 15);
  const int kr0   = (lane >> 4) * 8;
  FU bu[4];
#pragma unroll
  for (int ks = 0; ks < 4; ++ks){
    float wv[8];
#pragma unroll
    for (int j = 0; j < 8; ++j) wv[j] = W[(size_t)(ks*32 + kr0 + j)*NC + col];
#pragma unroll
    for (int q = 0; q < 4; ++q) bu[ks].u[q] = cvtpk(wv[2*q], wv[2*q+1]);
  }

  // stage A tile (128 rows x 128 k) as bf16, byte ^= (row&7)<<4
  for (int i = tid; i < 128*32; i += 512){
    int row = i >> 5, kq = i & 31;            // kq: 8-byte unit along k
    int rsrc = rb + row; if (rsrc >= n) rsrc = n - 1;
    uint2 dw;
    if (BIN){
      dw = ((const uint2*)Xv)[(size_t)rsrc*32 + kq];      // 4 bf16 copy
    } else {
      f4 xv = ((const f4*)Xv)[(size_t)rsrc*32 + kq];
      dw = make_uint2(cvtpk(xv[0], xv[1]), cvtpk(xv[2], xv[3]));
    }
    int byte = (row*256 + kq*8) ^ ((row & 7) << 4);
    *reinterpret_cast<uint2*>(Alds + byte) = dw;
  }
  __syncthreads();

  f4 acc[RT];
#pragma unroll
  for (int rt = 0; rt < RT; ++rt) acc[rt] = 0.0f;

#pragma unroll
  for (int rt = 0; rt < RT; ++rt){
    const int arow = (rt0 + rt)*16 + (lane & 15);
#pragma unroll
    for (int ks = 0; ks < 4; ++ks){
      int kb = ks*32 + kr0;
      int byte = (arow*256 + kb*2) ^ ((arow & 7) << 4);
      s8 a = *reinterpret_cast<const s8*>(Alds + byte);
      acc[rt] = __builtin_amdgcn_mfma_f32_16x16x32_bf16(a, bu[ks].s, acc[rt], 0, 0, 0);
    }
  }

#pragma unroll
  for (int rt = 0; rt < RT; ++rt){
    int rowb = rb + (rt0 + rt)*16 + 4*(lane >> 4);
#pragma unroll
    for (int r = 0; r < 4; ++r){
      int row = rowb + r;
      if (row < n) Yb[(size_t)row*NC + col] = (unsigned short)cvtpk(acc[rt][r], acc[rt][r]);
    }
  }
}

template<int NC, int BIN>
__global__ __launch_bounds__(512) void gemm_k(const void* __restrict__ X,
                                              const float* __restrict__ W,
                                              unsigned short* __restrict__ Yb, int n){
  __shared__ int4 AldsV[2048];
  gemm_body<NC, BIN>(X, W, Yb, n, blockIdx.x, (char*)AldsV);
}

// ---- fused: gemm1 (blocks < GB) || bucket-count (LDS hist, no global atomics)
// counts layout: counts[bin*CB + blk] (bin-major flat order)
__global__ __launch_bounds__(512) void fused1_k(const float* __restrict__ X,
                                                const float* __restrict__ W1,
                                                unsigned short* __restrict__ Yb,
                                                const void* __restrict__ eidx,
                                                const void* __restrict__ batchp,
                                                int* __restrict__ counts,
                                                int* __restrict__ batch32,
                                                int n, int e, int GB, int CB){
  __shared__ int4 AldsV[2048];
  __shared__ int hist[512];
  int blk = blockIdx.x;
  if (blk < GB){
    gemm_body<128, 0>(X, W1, Yb, n, blk, (char*)AldsV);
    return;
  }
  blk -= GB;                          // 0..CB-1
  const int NBK = (n + 127) >> 7;
  for (int i = threadIdx.x; i < NBK; i += 512) hist[i] = 0;
  __syncthreads();
  int is64 = detect64((const unsigned*)eidx, e);
  int CHK = (e + CB - 1) / CB;
  int beg = blk*CHK, end = min(e, beg + CHK);
  for (int i = beg + (int)threadIdx.x; i < end; i += 512){
    int d = ld_idx(eidx, e + i, is64);
    atomicAdd(&hist[d >> 7], 1);      // LDS atomic
  }
  __syncthreads();
  for (int i = threadIdx.x; i < NBK; i += 512) counts[i*CB + blk] = hist[i];
  for (int i = blk*512 + (int)threadIdx.x; i < n; i += CB*512)
    batch32[i] = ld_idx(batchp, i, is64);
}

// ---- flat scan level 1: block-local exclusive scan + block sums.
// CB == 256 == scan block size, so bucket boundaries align with scan blocks:
// bsum (after level 2) IS the bucket-base array.
__global__ void scanA_k(const int* __restrict__ counts, int* __restrict__ base,
                        int* __restrict__ bsum, int L){
  __shared__ int sh[256];
  int tid = threadIdx.x;
  int i = blockIdx.x*256 + tid;
  int v = (i < L) ? counts[i] : 0;
  sh[tid] = v; __syncthreads();
  for (int off = 1; off < 256; off <<= 1){
    int t = (tid >= off) ? sh[tid - off] : 0;
    __syncthreads();
    sh[tid] += t;
    __syncthreads();
  }
  if (i < L) base[i] = sh[tid] - v;
  if (tid == 255) bsum[blockIdx.x] = sh[255];
}

// ---- level 2: single block scans block sums (nb <= 512); misc init ----
__global__ __launch_bounds__(512) void scanB2_k(int* __restrict__ bsum, int nb,
                                                int* __restrict__ rowptr,
                                                float* __restrict__ outsum,
                                                int totalOut, int n, int e){
  __shared__ int sh[512];
  int tid = threadIdx.x;
  int v = (tid < nb) ? bsum[tid] : 0;
  sh[tid] = v; __syncthreads();
  for (int off = 1; off < 512; off <<= 1){
    int t = (tid >= off) ? sh[tid - off] : 0;
    __syncthreads();
    sh[tid] += t;
    __syncthreads();
  }
  if (tid < nb) bsum[tid] = sh[tid] - v;          // exclusive
  if (tid == nb - 1) bsum[nb] = sh[tid];          // total = e
  if (tid == 0) rowptr[n] = e;
  for (int k = tid; k < totalOut; k += 512) outsum[k] = 0.0f;
}

// ---- scatter edges into bucket-grouped array (LDS cursors) ----
__global__ __launch_bounds__(512) void scat_k(const void* __restrict__ eidx,
                                              const int* __restrict__ base,
                                              const int* __restrict__ bsum,
                                              int* __restrict__ packed,
                                              int n, int e, int CB){
  __shared__ int cur[512];
  int blk = blockIdx.x, tid = threadIdx.x;
  const int NBK = (n + 127) >> 7;
  for (int i = tid; i < NBK; i += 512) cur[i] = bsum[i] + base[i*CB + blk];
  __syncthreads();
  int is64 = detect64((const unsigned*)eidx, e);
  int CHK = (e + CB - 1) / CB;
  int beg = blk*CHK, end = min(e, beg + CHK);
  for (int i = beg + tid; i < end; i += 512){
    int s = ld_idx(eidx, i, is64);
    int d = ld_idx(eidx, e + i, is64);
    int pos = atomicAdd(&cur[d >> 7], 1);
    packed[pos] = s | ((d & 127) << 16);   // src < 65536 required
  }
}

// ---- per-bucket CSR build: 128-bin LDS counting sort, degrees, dinv ----
#define CSR_CAP 6144
__global__ __launch_bounds__(256) void csr_k(const int* __restrict__ packed,
                                             const int* __restrict__ bsum,
                                             int* __restrict__ esrcS,
                                             int* __restrict__ rowptr,
                                             float* __restrict__ dinv, int n){
  __shared__ int vals[CSR_CAP];
  __shared__ int hist[128], off[128], cur[128];
  int b = blockIdx.x, tid = threadIdx.x;
  int sbeg = bsum[b], send = bsum[b + 1];
  int m = send - sbeg;
  int mL = min(m, CSR_CAP);
  for (int i = tid; i < mL; i += 256) vals[i] = packed[sbeg + i];
  if (tid < 128) hist[tid] = 0;
  __syncthreads();
  for (int i = tid; i < m; i += 256){
    int v = (i < CSR_CAP) ? vals[i] : packed[sbeg + i];
    atomicAdd(&hist[(v >> 16) & 127], 1);
  }
  __syncthreads();
  if (tid < 128) off[tid] = hist[tid];
  __syncthreads();
  for (int o = 1; o < 128; o <<= 1){
    int v = 0;
    if (tid < 128 && tid >= o) v = off[tid - o];
    __syncthreads();
    if (tid < 128) off[tid] += v;
    __syncthreads();
  }
  if (tid < 128){
    int ex = off[tid] - hist[tid];      // exclusive
    cur[tid] = ex;
    int node = b*128 + tid;
    if (node < n){
      rowptr[node] = sbeg + ex;
      dinv[node] = rsqrtf((float)hist[tid] + 1.0f);
    }
  }
  __syncthreads();
  for (int i = tid; i < m; i += 256){
    int v = (i < CSR_CAP) ? vals[i] : packed[sbeg + i];
    int pos = atomicAdd(&cur[(v >> 16) & 127], 1);
    esrcS[sbeg + pos] = v & 0xFFFF;
  }
}

// ---- CSR aggregation + bias + relu: one wave per node, bf16 gathers,
// unroll-by-16 load-then-FMA (16 gathers in flight per wave).
// OB=1: emit bf16 (for gemm consumption); OB=0: emit f32 (for pool).
template<int NC, int OB>
__global__ __launch_bounds__(256) void agg_k(const unsigned short* __restrict__ HWb,
                                             const float* __restrict__ dinv,
                                             const int* __restrict__ rowptr,
                                             const int* __restrict__ esrcS,
                                             const float* __restrict__ bias,
                                             void* __restrict__ Hout, int n){
  int wid  = (blockIdx.x*256 + threadIdx.x) >> 6;
  int lane = threadIdx.x & 63;
  if (wid >= n) return;
  wid = __builtin_amdgcn_readfirstlane(wid);
  float di = dinv[wid];
  float di2 = di * di;
  int beg = __builtin_amdgcn_readfirstlane(rowptr[wid]);
  int end = __builtin_amdgcn_readfirstlane(rowptr[wid + 1]);
  if (NC == 128){
    unsigned sv = ((const unsigned*)(HWb + (size_t)wid*128))[lane];
    float a0 = bflo(sv) * di2, a1 = bfhi(sv) * di2;
    int j = beg;
    for (; j + 16 <= end; j += 16){
      int s[16]; float dv[16]; unsigned v[16];
#pragma unroll
      for (int t = 0; t < 16; ++t) s[t] = esrcS[j + t];
#pragma unroll
      for (int t = 0; t < 16; ++t){
        dv[t] = dinv[s[t]];
        v[t] = ((const unsigned*)(HWb + (size_t)s[t]*128))[lane];
      }
#pragma unroll
      for (int t = 0; t < 16; ++t){
        float wt = dv[t] * di;
        a0 += bflo(v[t]) * wt;
        a1 += bfhi(v[t]) * wt;
      }
    }
    for (; j + 4 <= end; j += 4){
      int s[4]; float dv[4]; unsigned v[4];
#pragma unroll
      for (int t = 0; t < 4; ++t) s[t] = esrcS[j + t];
#pragma unroll
      for (int t = 0; t < 4; ++t){
        dv[t] = dinv[s[t]];
        v[t] = ((const unsigned*)(HWb + (size_t)s[t]*128))[lane];
      }
#pragma unroll
      for (int t = 0; t < 4; ++t){
        float wt = dv[t] * di;
        a0 += bflo(v[t]) * wt;
        a1 += bfhi(v[t]) * wt;
      }
    }
    for (; j < end; ++j){
      int s = esrcS[j];
      float wt = dinv[s] * di;
      unsigned v = ((const unsigned*)(HWb + (size_t)s*128))[lane];
      a0 += bflo(v) * wt;
      a1 += bfhi(v) * wt;
    }
    f2 bb = ((const f2*)bias)[lane];
    a0 = fmaxf(a0 + bb[0], 0.0f);
    a1 = fmaxf(a1 + bb[1], 0.0f);
    if (OB){
      ((unsigned*)Hout)[(size_t)wid*64 + lane] = cvtpk(a0, a1);
    } else {
      f2 r; r[0] = a0; r[1] = a1;
      ((f2*)Hout)[(size_t)wid*64 + lane] = r;
    }
  } else {
    float acc = bflo((unsigned)HWb[(size_t)wid*64 + lane]) * di2;
    int j = beg;
    for (; j + 16 <= end; j += 16){
      int s[16]; float dv[16]; unsigned v[16];
#pragma unroll
      for (int t = 0; t < 16; ++t) s[t] = esrcS[j + t];
#pragma unroll
      for (int t = 0; t < 16; ++t){
        dv[t] = dinv[s[t]];
        v[t] = (unsigned)HWb[(size_t)s[t]*64 + lane];
      }
#pragma unroll
      for (int t = 0; t < 16; ++t) acc += bflo(v[t]) * (dv[t] * di);
    }
    for (; j + 4 <= end; j += 4){
      int s[4]; float dv[4]; unsigned v[4];
#pragma unroll
      for (int t = 0; t < 4; ++t) s[t] = esrcS[j + t];
#pragma unroll
      for (int t = 0; t < 4; ++t){
        dv[t] = dinv[s[t]];
        v[t] = (unsigned)HWb[(size_t)s[t]*64 + lane];
      }
#pragma unroll
      for (int t = 0; t < 4; ++t) acc += bflo(v[t]) * (dv[t] * di);
    }
    for (; j < end; ++j){
      int s = esrcS[j];
      acc += bflo((unsigned)HWb[(size_t)s*64 + lane]) * (dinv[s] * di);
    }
    acc = fmaxf(acc + bias[lane], 0.0f);
    ((float*)Hout)[(size_t)wid*64 + lane] = acc;
  }
}

// ---- mean pool: 8 nodes per wave, unrolled loads, run-length atomics ----
__global__ __launch_bounds__(256) void pool_k(const float* __restrict__ H2,
                                              const int* __restrict__ batch32,
                                              float* __restrict__ outsum, int n){
  int wid  = (blockIdx.x*256 + threadIdx.x) >> 6;
  int lane = threadIdx.x & 63;
  int start = wid * 8;
  if (start >= n) return;
  int cnt = min(8, n - start);
  float v[8]; int b[8];
#pragma unroll
  for (int t = 0; t < 8; ++t){
    int i = start + t; if (i >= n) i = n - 1;
    v[t] = H2[(size_t)i*64 + lane];
    b[t] = batch32[i];
  }
  float acc = 0.0f;
  int gcur = b[0];
#pragma unroll
  for (int t = 0; t < 8; ++t){
    if (t < cnt){
      if (b[t] != gcur){
        unsafeAtomicAdd(&outsum[gcur*64 + lane], acc);
        acc = 0.0f; gcur = b[t];
      }
      acc += v[t];
    }
  }
  unsafeAtomicAdd(&outsum[gcur*64 + lane], acc);
}

// ---- finalize: graph sizes via binary search on sorted batch + divide ----
__global__ void fin_k(const float* __restrict__ outsum,
                      const int* __restrict__ batch32,
                      float* __restrict__ out, int n, int g){
  __shared__ int starts[257];
  int t = threadIdx.x;
  if (t <= g){
    int lo = 0, hi = n;
    while (lo < hi){ int mid = (lo + hi) >> 1; if (batch32[mid] < t) lo = mid + 1; else hi = mid; }
    starts[t] = lo;
  }
  __syncthreads();
  for (int idx = t; idx < (g << 6); idx += 256){
    int gi = idx >> 6;
    float c = (float)(starts[gi + 1] - starts[gi]);
    out[idx] = outsum[idx] / fmaxf(c, 1.0f);
  }
}

extern "C" void kernel_launch(void* const* d_in, const int* in_sizes, int n_in,
                              void* d_out, int out_size, void* d_ws, size_t ws_size,
                              hipStream_t stream){
  const float* x    = (const float*)d_in[0];
  const float* W1   = (const float*)d_in[1];
  const float* b1   = (const float*)d_in[2];
  const float* W2   = (const float*)d_in[3];
  const float* b2   = (const float*)d_in[4];
  const void*  eidx = d_in[5];
  const void*  batchp = d_in[6];
  const int n = in_sizes[0] / 128;    // 50000
  const int e = in_sizes[5] / 2;      // 800000
  const int g = out_size / 64;        // 64 graphs
  float* out = (float*)d_out;

  const int NBK = (n + 127) >> 7;     // dst buckets (n <= 65536 required)
  const int CB  = 256;                // count/scatter blocks (== scan width)
  const int GB  = (n + 127) / 128;    // gemm M-tiles
  const int L   = NBK * CB;           // flat counts length

  // ---- workspace layout ----
  char* w = (char*)d_ws;
  int* counts  = (int*)w;                     // L   (bin-major)
  int* base    = counts + (size_t)L;          // L
  int* bsum    = base + (size_t)L;            // NBK+1 (nb2 == NBK)
  int* rowptr  = bsum + (NBK + 1);            // n+1
  int* batch32 = rowptr + (n + 1);            // n
  float* dinv  = (float*)(batch32 + n);       // n
  float* outsum = dinv + n;                   // out_size
  int* packed  = (int*)(outsum + out_size);   // e
  int* esrcS   = packed + e;                  // e
  size_t ofs = (size_t)((char*)(esrcS + e) - w);
  ofs = (ofs + 255) & ~(size_t)255;
  unsigned short* HWb = (unsigned short*)(w + ofs);   // n*128 bf16 (gemm out)
  size_t ofs2 = ofs + (size_t)n * 128 * 2;
  ofs2 = (ofs2 + 255) & ~(size_t)255;
  unsigned short* Hb = (unsigned short*)(w + ofs2);   // n*128 bf16 (h1)
  size_t ofs3 = ofs2 + (size_t)n * 128 * 2;
  ofs3 = (ofs3 + 255) & ~(size_t)255;
  float* H2 = (float*)(w + ofs3);             // n*64 f32 (h2)

  fused1_k<<<GB + CB, 512, 0, stream>>>(x, W1, HWb, eidx, batchp,
                                        counts, batch32, n, e, GB, CB);
  scanA_k<<<NBK, 256, 0, stream>>>(counts, base, bsum, L);
  scanB2_k<<<1, 512, 0, stream>>>(bsum, NBK, rowptr, outsum, out_size, n, e);
  scat_k<<<CB, 512, 0, stream>>>(eidx, base, bsum, packed, n, e, CB);
  csr_k<<<NBK, 256, 0, stream>>>(packed, bsum, esrcS, rowptr, dinv, n);

  agg_k<128, 1><<<(n + 3)/4, 256, 0, stream>>>(HWb, dinv, rowptr, esrcS, b1, Hb, n);
  gemm_k<64, 1><<<GB, 512, 0, stream>>>(Hb, W2, HWb, n);
  agg_k<64, 0><<<(n + 3)/4, 256, 0, stream>>>(HWb, dinv, rowptr, esrcS, b2, H2, n);

  int pw = (n + 7)/8;
  pool_k<<<(pw + 3)/4, 256, 0, stream>>>(H2, batch32, outsum, n);
  fin_k<<<1, 256, 0, stream>>>(outsum, batch32, out, n, g);
}